// Round 6
// baseline (4634.993 us; speedup 1.0000x reference)
//
#include <hip/hip_runtime.h>
#include <hip/hip_bf16.h>
#include <hip/hip_fp16.h>

typedef _Float16 v2h __attribute__((ext_vector_type(2)));

__device__ __forceinline__ float fdot2u(unsigned int a, unsigned int b, float c){
  return __builtin_amdgcn_fdot2(__builtin_bit_cast(v2h, a), __builtin_bit_cast(v2h, b), c, false);
}
__device__ __forceinline__ unsigned int packh2(float a, float b){
  union{ _Float16 h[2]; unsigned int u; } z;
  z.h[0] = (_Float16)a; z.h[1] = (_Float16)b; return z.u;
}
__device__ __forceinline__ float h2f(unsigned short s){
  return (float)__builtin_bit_cast(_Float16, s);
}
__device__ __forceinline__ float sigf(float x){
  return __builtin_amdgcn_rcpf(1.0f + __builtin_amdgcn_exp2f(-1.44269504f*x));
}
__device__ __forceinline__ float tanhf_(float x){
  return 2.0f*__builtin_amdgcn_rcpf(1.0f + __builtin_amdgcn_exp2f(-2.88539008f*x)) - 1.0f;
}
// quad_perm DPP lane swaps (pure VALU, no LDS): xor1 = [1,0,3,2], xor2 = [2,3,0,1]
__device__ __forceinline__ float dpp_xor1(float x){
  return __builtin_bit_cast(float,
    __builtin_amdgcn_mov_dpp(__builtin_bit_cast(int, x), 0xB1, 0xF, 0xF, true));
}
__device__ __forceinline__ float dpp_xor2(float x){
  return __builtin_bit_cast(float,
    __builtin_amdgcn_mov_dpp(__builtin_bit_cast(int, x), 0x4E, 0xF, 0xF, true));
}

// ---------------- Kernel A: weight conversion (K-split chunk layout) ----------------
// whhT2 uint4 index = (g*8+j)*1024 + (u*4+p), dword l:
//   holds W_hh[g*256+u][k] pair for dword d = p*32 + j*4 + l (k = 2d, 2d+1).
__global__ void prep_kernel(const float* __restrict__ Whh, const float* __restrict__ Wfc,
                            const float* __restrict__ bih, const float* __restrict__ bhh,
                            unsigned int* __restrict__ whhT2, unsigned int* __restrict__ wfc16,
                            float* __restrict__ bsum){
  int i = blockIdx.x*256 + threadIdx.x;
  if (i < 131072){                       // W_hh (1024 x 256) f32 -> f16 pair dwords
    int r = i >> 7, d = i & 127;
    int g = r >> 8, u = r & 255;
    int p = d >> 5, j = (d >> 2) & 7, l = d & 3;
    whhT2[(size_t)((g*8+j)*1024 + u*4 + p)*4 + l] = packh2(Whh[r*256 + 2*d], Whh[r*256 + 2*d + 1]);
  } else if (i < 139264){                // W_fc (64 x 256) -> (64 x 128)
    int j = i - 131072; int o = j >> 7, d = j & 127;
    wfc16[j] = packh2(Wfc[o*256 + 2*d], Wfc[o*256 + 2*d + 1]);
  } else if (i < 140288){                // bsum = b_ih + b_hh
    int g = i - 139264;
    bsum[g] = bih[g] + bhh[g];
  }
}

// ---------------- Kernel B: x_proj = x @ W_ih^T + bsum (f16 out) ----------------
#define XS 68
__global__ __launch_bounds__(256) void xproj_kernel(const float* __restrict__ x,
                          const float* __restrict__ Wih,
                          const float* __restrict__ bsum, unsigned int* __restrict__ xproj){
  __shared__ unsigned int lx[128*XS];
  __shared__ unsigned int lw[64*XS];
  __shared__ float lb[64];
  int t  = threadIdx.x;
  int bt0 = blockIdx.x*128, g0 = blockIdx.y*64;
  int rr = t >> 4, cc = t & 15;
  #pragma unroll
  for (int it=0; it<8; ++it){
    int row = rr + it*16;
    const float4* s = (const float4*)(x + (size_t)(bt0+row)*128 + cc*8);
    float4 a = s[0], b = s[1];
    uint4 w; w.x=packh2(a.x,a.y); w.y=packh2(a.z,a.w); w.z=packh2(b.x,b.y); w.w=packh2(b.z,b.w);
    *(uint4*)&lx[row*XS + cc*4] = w;
  }
  #pragma unroll
  for (int it=0; it<4; ++it){
    int row = rr + it*16;
    const float4* s = (const float4*)(Wih + (size_t)(g0+row)*128 + cc*8);
    float4 a = s[0], b = s[1];
    uint4 w; w.x=packh2(a.x,a.y); w.y=packh2(a.z,a.w); w.z=packh2(b.x,b.y); w.w=packh2(b.z,b.w);
    *(uint4*)&lw[row*XS + cc*4] = w;
  }
  if (t < 64) lb[t] = bsum[g0 + t];
  __syncthreads();

  float acc[8][4];
  #pragma unroll
  for (int j=0;j<8;++j)
    #pragma unroll
    for (int i=0;i<4;++i) acc[j][i]=0.f;

  #pragma unroll
  for (int d4=0; d4<16; ++d4){
    uint4 wv[4], xv[8];
    #pragma unroll
    for (int i=0;i<4;++i) wv[i] = *(const uint4*)&lw[(cc*4+i)*XS + d4*4];
    #pragma unroll
    for (int j=0;j<8;++j) xv[j] = *(const uint4*)&lx[(rr*8+j)*XS + d4*4];
    #pragma unroll
    for (int j=0;j<8;++j){
      #pragma unroll
      for (int i=0;i<4;++i){
        float a = acc[j][i];
        a = fdot2u(xv[j].x, wv[i].x, a);
        a = fdot2u(xv[j].y, wv[i].y, a);
        a = fdot2u(xv[j].z, wv[i].z, a);
        a = fdot2u(xv[j].w, wv[i].w, a);
        acc[j][i] = a;
      }
    }
  }
  #pragma unroll
  for (int j=0;j<8;++j){
    int bt = bt0 + rr*8 + j;
    uint2 o2;
    o2.x = packh2(acc[j][0]+lb[cc*4+0], acc[j][1]+lb[cc*4+1]);
    o2.y = packh2(acc[j][2]+lb[cc*4+2], acc[j][3]+lb[cc*4+3]);
    *(uint2*)&xproj[(size_t)bt*512 + (g0>>1) + cc*2] = o2;
  }
}

// ---------------- Kernel C: recurrent LSTM (K-split + DPP + global-streamed W) ----------------
// 1024 threads/WG, 1 WG/batch. Thread t = u*4+p: unit u (0..255), K-quarter p.
// Gates i,f,g (24 uint4) resident in regs. Gate o (8 uint4): chunks 24,25 in
// LDS ([chunk][thread], conflict-free), chunks 26..31 streamed from GLOBAL
// every step (L2-resident: same 96KB shared by all 32 CUs; VMEM pipe was idle
// while LDS was saturated). Address laundered via empty asm to defeat LICM
// (otherwise 24 dwords of loop-invariant loads get hoisted into registers).
// h: 4 bank-shifted replicas (stride 132 dwords), double-buffered.
// Reduce/exchange: quad_perm DPP butterfly. ONE barrier per step.
#define WL4 2
#define HOFF (WL4*4096)            // dword offset of h replicas
#define HBUF 528                   // 4 replicas x 132 dwords

#define DOTJ(J, WO) { \
    uint4 h4 = *(const uint4*)(hb + (J)*4); \
    A0 = fdot2u(w4[0][J].x, h4.x, A0); A0 = fdot2u(w4[0][J].y, h4.y, A0); \
    A0 = fdot2u(w4[0][J].z, h4.z, A0); A0 = fdot2u(w4[0][J].w, h4.w, A0); \
    A1 = fdot2u(w4[1][J].x, h4.x, A1); A1 = fdot2u(w4[1][J].y, h4.y, A1); \
    A1 = fdot2u(w4[1][J].z, h4.z, A1); A1 = fdot2u(w4[1][J].w, h4.w, A1); \
    A2 = fdot2u(w4[2][J].x, h4.x, A2); A2 = fdot2u(w4[2][J].y, h4.y, A2); \
    A2 = fdot2u(w4[2][J].z, h4.z, A2); A2 = fdot2u(w4[2][J].w, h4.w, A2); \
    A3 = fdot2u((WO).x, h4.x, A3); A3 = fdot2u((WO).y, h4.y, A3); \
    A3 = fdot2u((WO).z, h4.z, A3); A3 = fdot2u((WO).w, h4.w, A3); }

extern "C" __global__ void __launch_bounds__(1024,4) lstm_kernel(
    const unsigned int* __restrict__ whhT2, const unsigned int* __restrict__ xproj,
    unsigned short* __restrict__ h_all)
{
  extern __shared__ unsigned int lds[];
  uint4* lw4 = (uint4*)lds;
  unsigned short* lds16 = (unsigned short*)lds;
  const int t = threadIdx.x;
  const int u = t >> 2, p = t & 3;
  const int b = blockIdx.x;
  const int p164 = p*164;          // p*132 (replica base) + p*32 (K-quarter start)

  const uint4* wsrc = (const uint4*)whhT2;
  uint4 w4[3][8];
  #pragma unroll
  for (int g=0; g<3; ++g)
    #pragma unroll
    for (int j=0; j<8; ++j) w4[g][j] = wsrc[(g*8+j)*1024 + t];
  #pragma unroll
  for (int q=0; q<WL4; ++q) lw4[q*1024 + t] = wsrc[(24+q)*1024 + t];
  if (t < HBUF) lds[HOFF + t] = 0u;     // buffer 0 replicas = zeros for step 0

  const unsigned long long gbase = (unsigned long long)(wsrc + 26*1024 + t);

  const float m0 = (p==0)?1.f:0.f, m1 = (p==1)?1.f:0.f,
              m2 = (p==2)?1.f:0.f, m3 = (p==3)?1.f:0.f;
  const unsigned short* xpb = (const unsigned short*)xproj + (size_t)b*2048*1024;
  const int xoff = p*256 + u;           // row p*256+u of x_proj
  unsigned short xn = xpb[xoff];
  float c = 0.f;
  unsigned short* hout = h_all + (size_t)b*2048*256 + u;
  __syncthreads();

  for (int tt=0; tt<2048; ++tt){
    const int cur = tt & 1;
    // launder streamed-weight base: opaque each iteration -> no LICM
    unsigned long long ga = gbase;
    asm volatile("" : "+v"(ga));
    const uint4* gp = (const uint4*)ga;
    // issue first 4 streamed chunks early (independent of h)
    uint4 wg0 = gp[0*1024];
    uint4 wg1 = gp[1*1024];
    uint4 wg2 = gp[2*1024];
    uint4 wg3 = gp[3*1024];

    float A0 = 0.f, A1 = 0.f, A2 = 0.f, A3 = 0.f;
    float xv = h2f(xn);
    // prefetch next step's x_proj value
    int tn = (tt+1 < 2048) ? tt+1 : 2047;
    xn = xpb[(size_t)tn*1024 + xoff];

    const unsigned int* hb = lds + HOFF + cur*HBUF + p164;
    // j=0,1: gate-o from LDS
    {
      uint4 wo0 = lw4[0*1024 + t];
      DOTJ(0, wo0);
      uint4 wo1 = lw4[1*1024 + t];
      DOTJ(1, wo1);
    }
    // j=2..7: gate-o from global (L2), software-pipelined
    DOTJ(2, wg0);
    uint4 wg4 = gp[4*1024];
    DOTJ(3, wg1);
    uint4 wg5 = gp[5*1024];
    DOTJ(4, wg2);
    DOTJ(5, wg3);
    DOTJ(6, wg4);
    DOTJ(7, wg5);

    // inject x_proj pre-act into this thread's gate slot p
    A0 = fmaf(m0, xv, A0); A1 = fmaf(m1, xv, A1);
    A2 = fmaf(m2, xv, A2); A3 = fmaf(m3, xv, A3);
    // butterfly sum over K-quarters: quad_perm DPP (VALU only, no LDS)
    A0 += dpp_xor1(A0); A1 += dpp_xor1(A1);
    A2 += dpp_xor1(A2); A3 += dpp_xor1(A3);
    A0 += dpp_xor2(A0); A1 += dpp_xor2(A1);
    A2 += dpp_xor2(A2); A3 += dpp_xor2(A3);

    float gi = sigf(A0);
    float gf = sigf(A1);
    float gg = tanhf_(A2);
    float go = sigf(A3);
    c = gf*c + gi*gg;
    float h = go * tanhf_(c);
    unsigned short hh = __builtin_bit_cast(unsigned short, (_Float16)h);
    // publish h to this thread's replica p of the next buffer
    lds16[(HOFF + (cur^1)*HBUF + p*132)*2 + u] = hh;
    if (p == 0) hout[(size_t)tt*256] = hh;     // h_all for fc phase
    __syncthreads();
  }
}

// ---------------- Kernel D: logits = h @ W_fc^T + b_fc ; softmax over O=64 ----------------
__global__ __launch_bounds__(1024) void fc_softmax_kernel(const unsigned short* __restrict__ h_all,
      const unsigned int* __restrict__ wfc16, const float* __restrict__ bfc,
      float* __restrict__ out){
  __shared__ unsigned int lwf[64*132];
  __shared__ unsigned int lh[16*132];
  int t = threadIdx.x;
  int bt0 = blockIdx.x*16;
  {
    const uint4* s = (const uint4*)(wfc16 + (size_t)t*8);
    uint4 a = s[0], b = s[1];
    unsigned int* dst = &lwf[(t>>4)*132 + (t&15)*8];
    *(uint4*)dst = a; *(uint4*)(dst+4) = b;
  }
  {
    int row = t>>6, col = (t&63)*2;
    const unsigned int* hsrc = (const unsigned int*)h_all;
    uint2 v = *(const uint2*)(hsrc + (size_t)(bt0+row)*128 + col);
    *(uint2*)&lh[row*132 + col] = v;
  }
  __syncthreads();
  int w = t>>6, o = t&63;
  int bt = bt0 + w;
  float acc = bfc[o];
  #pragma unroll
  for (int d4=0; d4<32; ++d4){
    uint4 hq = *(const uint4*)&lh[w*132 + d4*4];
    uint4 wq = *(const uint4*)&lwf[o*132 + d4*4];
    acc = fdot2u(wq.x, hq.x, acc);
    acc = fdot2u(wq.y, hq.y, acc);
    acc = fdot2u(wq.z, hq.z, acc);
    acc = fdot2u(wq.w, hq.w, acc);
  }
  float m = acc;
  #pragma unroll
  for (int off=32; off>=1; off>>=1) m = fmaxf(m, __shfl_xor(m, off));
  float e = __builtin_amdgcn_exp2f(1.44269504f*(acc - m));
  float s = e;
  #pragma unroll
  for (int off=32; off>=1; off>>=1) s += __shfl_xor(s, off);
  out[(size_t)bt*64 + o] = e * __builtin_amdgcn_rcpf(s);
}

// ---------------- launch ----------------
extern "C" void kernel_launch(void* const* d_in, const int* in_sizes, int n_in,
                              void* d_out, int out_size, void* d_ws, size_t ws_size,
                              hipStream_t stream){
  const float* x   = (const float*)d_in[0];
  const float* Wih = (const float*)d_in[1];
  const float* Whh = (const float*)d_in[2];
  const float* bih = (const float*)d_in[3];
  const float* bhh = (const float*)d_in[4];
  const float* Wfc = (const float*)d_in[5];
  const float* bfc = (const float*)d_in[6];
  float* out = (float*)d_out;

  char* ws = (char*)d_ws;
  unsigned int*   xproj = (unsigned int*)ws;                         // 128 MB (f16 pairs)
  unsigned short* h_all = (unsigned short*)(ws + 134217728);         // 32 MB (f16)
  unsigned int*   whhT2 = (unsigned int*)(ws + 134217728 + 33554432);// 512 KB (chunked)
  unsigned int*   wfc16 = whhT2 + 131072;                            // 32 KB
  float*          bsum  = (float*)(wfc16 + 8192);                    // 4 KB

  prep_kernel<<<548, 256, 0, stream>>>(Whh, Wfc, bih, bhh, whhT2, wfc16, bsum);
  dim3 gb(512, 16);
  xproj_kernel<<<gb, 256, 0, stream>>>(x, Wih, bsum, xproj);
  int dyn = (HOFF + 2*HBUF) * 4;   // 36,992 B dynamic LDS
  hipFuncSetAttribute((const void*)lstm_kernel, hipFuncAttributeMaxDynamicSharedMemorySize, dyn);
  lstm_kernel<<<32, 1024, dyn, stream>>>(whhT2, xproj, h_all);
  fc_softmax_kernel<<<4096, 1024, 0, stream>>>(h_all, wfc16, bfc, out);
}

// Round 7
// 3042.883 us; speedup vs baseline: 1.5232x; 1.5232x over previous
//
#include <hip/hip_runtime.h>
#include <hip/hip_bf16.h>
#include <hip/hip_fp16.h>

typedef _Float16 v2h __attribute__((ext_vector_type(2)));

__device__ __forceinline__ float fdot2u(unsigned int a, unsigned int b, float c){
  return __builtin_amdgcn_fdot2(__builtin_bit_cast(v2h, a), __builtin_bit_cast(v2h, b), c, false);
}
__device__ __forceinline__ unsigned int packh2(float a, float b){
  union{ _Float16 h[2]; unsigned int u; } z;
  z.h[0] = (_Float16)a; z.h[1] = (_Float16)b; return z.u;
}
__device__ __forceinline__ float h2f(unsigned short s){
  return (float)__builtin_bit_cast(_Float16, s);
}
__device__ __forceinline__ float sigf(float x){
  return __builtin_amdgcn_rcpf(1.0f + __builtin_amdgcn_exp2f(-1.44269504f*x));
}
__device__ __forceinline__ float tanhf_(float x){
  return 2.0f*__builtin_amdgcn_rcpf(1.0f + __builtin_amdgcn_exp2f(-2.88539008f*x)) - 1.0f;
}
// quad_perm [1,0,3,2]: swap lane pairs (p0<->p1) — pure VALU
__device__ __forceinline__ float dpp_xor1(float x){
  return __builtin_bit_cast(float,
    __builtin_amdgcn_mov_dpp(__builtin_bit_cast(int, x), 0xB1, 0xF, 0xF, true));
}

// ---------------- Kernel A: weight conversion (K-half chunk layout) ----------------
// whhT3 uint4 index = (g*16+j)*512 + (u*2+p), dword l:
//   holds W_hh[g*256+u][k] pair for dword d = p*64 + j*4 + l (k = 2d, 2d+1).
__global__ void prep_kernel(const float* __restrict__ Whh, const float* __restrict__ Wfc,
                            const float* __restrict__ bih, const float* __restrict__ bhh,
                            unsigned int* __restrict__ whhT3, unsigned int* __restrict__ wfc16,
                            float* __restrict__ bsum){
  int i = blockIdx.x*256 + threadIdx.x;
  if (i < 131072){                       // W_hh (1024 x 256) f32 -> f16 pair dwords
    int r = i >> 7, d = i & 127;
    int g = r >> 8, u = r & 255;
    int p = (d >> 6) & 1, j = (d >> 2) & 15, l = d & 3;
    whhT3[(size_t)((g*16+j)*512 + u*2 + p)*4 + l] = packh2(Whh[r*256 + 2*d], Whh[r*256 + 2*d + 1]);
  } else if (i < 139264){                // W_fc (64 x 256) -> (64 x 128)
    int j = i - 131072; int o = j >> 7, d = j & 127;
    wfc16[j] = packh2(Wfc[o*256 + 2*d], Wfc[o*256 + 2*d + 1]);
  } else if (i < 140288){                // bsum = b_ih + b_hh
    int g = i - 139264;
    bsum[g] = bih[g] + bhh[g];
  }
}

// ---------------- Kernel B: x_proj = x @ W_ih^T + bsum (f16 out) ----------------
#define XS 68
__global__ __launch_bounds__(256) void xproj_kernel(const float* __restrict__ x,
                          const float* __restrict__ Wih,
                          const float* __restrict__ bsum, unsigned int* __restrict__ xproj){
  __shared__ unsigned int lx[128*XS];
  __shared__ unsigned int lw[64*XS];
  __shared__ float lb[64];
  int t  = threadIdx.x;
  int bt0 = blockIdx.x*128, g0 = blockIdx.y*64;
  int rr = t >> 4, cc = t & 15;
  #pragma unroll
  for (int it=0; it<8; ++it){
    int row = rr + it*16;
    const float4* s = (const float4*)(x + (size_t)(bt0+row)*128 + cc*8);
    float4 a = s[0], b = s[1];
    uint4 w; w.x=packh2(a.x,a.y); w.y=packh2(a.z,a.w); w.z=packh2(b.x,b.y); w.w=packh2(b.z,b.w);
    *(uint4*)&lx[row*XS + cc*4] = w;
  }
  #pragma unroll
  for (int it=0; it<4; ++it){
    int row = rr + it*16;
    const float4* s = (const float4*)(Wih + (size_t)(g0+row)*128 + cc*8);
    float4 a = s[0], b = s[1];
    uint4 w; w.x=packh2(a.x,a.y); w.y=packh2(a.z,a.w); w.z=packh2(b.x,b.y); w.w=packh2(b.z,b.w);
    *(uint4*)&lw[row*XS + cc*4] = w;
  }
  if (t < 64) lb[t] = bsum[g0 + t];
  __syncthreads();

  float acc[8][4];
  #pragma unroll
  for (int j=0;j<8;++j)
    #pragma unroll
    for (int i=0;i<4;++i) acc[j][i]=0.f;

  #pragma unroll
  for (int d4=0; d4<16; ++d4){
    uint4 wv[4], xv[8];
    #pragma unroll
    for (int i=0;i<4;++i) wv[i] = *(const uint4*)&lw[(cc*4+i)*XS + d4*4];
    #pragma unroll
    for (int j=0;j<8;++j) xv[j] = *(const uint4*)&lx[(rr*8+j)*XS + d4*4];
    #pragma unroll
    for (int j=0;j<8;++j){
      #pragma unroll
      for (int i=0;i<4;++i){
        float a = acc[j][i];
        a = fdot2u(xv[j].x, wv[i].x, a);
        a = fdot2u(xv[j].y, wv[i].y, a);
        a = fdot2u(xv[j].z, wv[i].z, a);
        a = fdot2u(xv[j].w, wv[i].w, a);
        acc[j][i] = a;
      }
    }
  }
  #pragma unroll
  for (int j=0;j<8;++j){
    int bt = bt0 + rr*8 + j;
    uint2 o2;
    o2.x = packh2(acc[j][0]+lb[cc*4+0], acc[j][1]+lb[cc*4+1]);
    o2.y = packh2(acc[j][2]+lb[cc*4+2], acc[j][3]+lb[cc*4+3]);
    *(uint2*)&xproj[(size_t)bt*512 + (g0>>1) + cc*2] = o2;
  }
}

// ---------------- Kernel C: recurrent LSTM (512 thr, 256 VGPR, K-half split) ----------------
// 512 threads/WG (2 waves/SIMD -> 256 unified regs, all allocatable as true
// VGPRs: no accvgpr-copy tax). Thread t = u*2+p: ALL 4 gates of unit u over
// K-half p. Weights 64 uint4/thread: j=0..12 in VGPRs (208 dwords), j=13..15
// streamed from LDS each step ([chunk][thread], conflict-free b128; base
// laundered per-iteration to defeat LICM). h single-copy double-buffered
// (2-way bank alias = free), 16 broadcast b128 reads/thread. Pair-reduce:
// one quad_perm DPP add per gate. ONE barrier per step.
#define WRJ 13                       // reg-resident chunks per gate
#define WLJ 3                        // LDS-streamed chunks per gate
#define HOFF (4*WLJ*512*4)           // dword offset of h double-buffer (24576)

extern "C" __global__ void __launch_bounds__(512,2) lstm_kernel(
    const unsigned int* __restrict__ whhT3, const unsigned int* __restrict__ xproj,
    unsigned short* __restrict__ h_all)
{
  extern __shared__ unsigned int lds[];
  uint4* lw4 = (uint4*)lds;
  unsigned short* lds16 = (unsigned short*)lds;
  const int t = threadIdx.x;
  const int u = t >> 1, p = t & 1;
  const int b = blockIdx.x;

  const uint4* wsrc = (const uint4*)whhT3;
  uint4 w0[WRJ], w1[WRJ], w2[WRJ], w3[WRJ];
  #pragma unroll
  for (int j=0; j<WRJ; ++j){
    w0[j] = wsrc[(0*16+j)*512 + t];
    w1[j] = wsrc[(1*16+j)*512 + t];
    w2[j] = wsrc[(2*16+j)*512 + t];
    w3[j] = wsrc[(3*16+j)*512 + t];
  }
  #pragma unroll
  for (int g=0; g<4; ++g)
    #pragma unroll
    for (int jj=0; jj<WLJ; ++jj)
      lw4[(g*WLJ+jj)*512 + t] = wsrc[(g*16+WRJ+jj)*512 + t];
  if (t < 256) lds[HOFF + t] = 0u;   // zero both h buffers (step 0 reads zeros)

  const float mp = (p==0) ? 1.f : 0.f;
  const unsigned short* xpb = (const unsigned short*)xproj + (size_t)b*2048*1024;
  unsigned short xn0 = xpb[u], xn1 = xpb[256+u], xn2 = xpb[512+u], xn3 = xpb[768+u];
  float c = 0.f;
  unsigned short* hout = h_all + (size_t)b*2048*256 + u;
  __syncthreads();

  for (int tt=0; tt<2048; ++tt){
    const int cur = tt & 1;
    float xv0 = h2f(xn0), xv1 = h2f(xn1), xv2 = h2f(xn2), xv3 = h2f(xn3);
    // prefetch next step's x_proj pre-acts (4 gate rows of unit u)
    int tn = (tt+1 < 2048) ? tt+1 : 2047;
    {
      const unsigned short* xr = xpb + (size_t)tn*1024;
      xn0 = xr[u]; xn1 = xr[256+u]; xn2 = xr[512+u]; xn3 = xr[768+u];
    }
    float A0 = 0.f, A1 = 0.f, A2 = 0.f, A3 = 0.f;
    const unsigned int* hb = lds + HOFF + cur*128 + p*64;

    // launder LDS weight base each iteration: defeat LICM hoisting 48 dwords
    int zoff = 0;
    asm volatile("" : "+v"(zoff));
    const uint4* lwl = lw4 + zoff;

    // streamed chunks j=13..15 (issue LDS reads early; consumed below)
    uint4 h4s[WLJ], wg0[WLJ], wg1[WLJ], wg2[WLJ], wg3[WLJ];
    #pragma unroll
    for (int jj=0; jj<WLJ; ++jj){
      h4s[jj] = *(const uint4*)(hb + (WRJ+jj)*4);
      wg0[jj] = lwl[(0*WLJ+jj)*512 + t];
      wg1[jj] = lwl[(1*WLJ+jj)*512 + t];
      wg2[jj] = lwl[(2*WLJ+jj)*512 + t];
      wg3[jj] = lwl[(3*WLJ+jj)*512 + t];
    }

    #pragma unroll
    for (int j=0; j<WRJ; ++j){
      uint4 h4 = *(const uint4*)(hb + j*4);
      A0 = fdot2u(w0[j].x, h4.x, A0); A0 = fdot2u(w0[j].y, h4.y, A0);
      A0 = fdot2u(w0[j].z, h4.z, A0); A0 = fdot2u(w0[j].w, h4.w, A0);
      A1 = fdot2u(w1[j].x, h4.x, A1); A1 = fdot2u(w1[j].y, h4.y, A1);
      A1 = fdot2u(w1[j].z, h4.z, A1); A1 = fdot2u(w1[j].w, h4.w, A1);
      A2 = fdot2u(w2[j].x, h4.x, A2); A2 = fdot2u(w2[j].y, h4.y, A2);
      A2 = fdot2u(w2[j].z, h4.z, A2); A2 = fdot2u(w2[j].w, h4.w, A2);
      A3 = fdot2u(w3[j].x, h4.x, A3); A3 = fdot2u(w3[j].y, h4.y, A3);
      A3 = fdot2u(w3[j].z, h4.z, A3); A3 = fdot2u(w3[j].w, h4.w, A3);
    }
    #pragma unroll
    for (int jj=0; jj<WLJ; ++jj){
      uint4 h4 = h4s[jj];
      A0 = fdot2u(wg0[jj].x, h4.x, A0); A0 = fdot2u(wg0[jj].y, h4.y, A0);
      A0 = fdot2u(wg0[jj].z, h4.z, A0); A0 = fdot2u(wg0[jj].w, h4.w, A0);
      A1 = fdot2u(wg1[jj].x, h4.x, A1); A1 = fdot2u(wg1[jj].y, h4.y, A1);
      A1 = fdot2u(wg1[jj].z, h4.z, A1); A1 = fdot2u(wg1[jj].w, h4.w, A1);
      A2 = fdot2u(wg2[jj].x, h4.x, A2); A2 = fdot2u(wg2[jj].y, h4.y, A2);
      A2 = fdot2u(wg2[jj].z, h4.z, A2); A2 = fdot2u(wg2[jj].w, h4.w, A2);
      A3 = fdot2u(wg3[jj].x, h4.x, A3); A3 = fdot2u(wg3[jj].y, h4.y, A3);
      A3 = fdot2u(wg3[jj].z, h4.z, A3); A3 = fdot2u(wg3[jj].w, h4.w, A3);
    }

    // add x_proj pre-acts exactly once (p==0 lane of each pair)
    A0 = fmaf(mp, xv0, A0); A1 = fmaf(mp, xv1, A1);
    A2 = fmaf(mp, xv2, A2); A3 = fmaf(mp, xv3, A3);
    // pair-reduce over K-halves: one DPP add per gate
    A0 += dpp_xor1(A0); A1 += dpp_xor1(A1);
    A2 += dpp_xor1(A2); A3 += dpp_xor1(A3);

    float gi = sigf(A0);
    float gf = sigf(A1);
    float gg = tanhf_(A2);
    float go = sigf(A3);
    c = gf*c + gi*gg;
    float h = go * tanhf_(c);
    unsigned short hh = __builtin_bit_cast(unsigned short, (_Float16)h);
    if (p == 0){
      lds16[(HOFF + (cur^1)*128)*2 + u] = hh;   // next step's h
      hout[(size_t)tt*256] = hh;                // h_all for fc phase
    }
    __syncthreads();
  }
}

// ---------------- Kernel D: logits = h @ W_fc^T + b_fc ; softmax over O=64 ----------------
__global__ __launch_bounds__(1024) void fc_softmax_kernel(const unsigned short* __restrict__ h_all,
      const unsigned int* __restrict__ wfc16, const float* __restrict__ bfc,
      float* __restrict__ out){
  __shared__ unsigned int lwf[64*132];
  __shared__ unsigned int lh[16*132];
  int t = threadIdx.x;
  int bt0 = blockIdx.x*16;
  {
    const uint4* s = (const uint4*)(wfc16 + (size_t)t*8);
    uint4 a = s[0], b = s[1];
    unsigned int* dst = &lwf[(t>>4)*132 + (t&15)*8];
    *(uint4*)dst = a; *(uint4*)(dst+4) = b;
  }
  {
    int row = t>>6, col = (t&63)*2;
    const unsigned int* hsrc = (const unsigned int*)h_all;
    uint2 v = *(const uint2*)(hsrc + (size_t)(bt0+row)*128 + col);
    *(uint2*)&lh[row*132 + col] = v;
  }
  __syncthreads();
  int w = t>>6, o = t&63;
  int bt = bt0 + w;
  float acc = bfc[o];
  #pragma unroll
  for (int d4=0; d4<32; ++d4){
    uint4 hq = *(const uint4*)&lh[w*132 + d4*4];
    uint4 wq = *(const uint4*)&lwf[o*132 + d4*4];
    acc = fdot2u(wq.x, hq.x, acc);
    acc = fdot2u(wq.y, hq.y, acc);
    acc = fdot2u(wq.z, hq.z, acc);
    acc = fdot2u(wq.w, hq.w, acc);
  }
  float m = acc;
  #pragma unroll
  for (int off=32; off>=1; off>>=1) m = fmaxf(m, __shfl_xor(m, off));
  float e = __builtin_amdgcn_exp2f(1.44269504f*(acc - m));
  float s = e;
  #pragma unroll
  for (int off=32; off>=1; off>>=1) s += __shfl_xor(s, off);
  out[(size_t)bt*64 + o] = e * __builtin_amdgcn_rcpf(s);
}

// ---------------- launch ----------------
extern "C" void kernel_launch(void* const* d_in, const int* in_sizes, int n_in,
                              void* d_out, int out_size, void* d_ws, size_t ws_size,
                              hipStream_t stream){
  const float* x   = (const float*)d_in[0];
  const float* Wih = (const float*)d_in[1];
  const float* Whh = (const float*)d_in[2];
  const float* bih = (const float*)d_in[3];
  const float* bhh = (const float*)d_in[4];
  const float* Wfc = (const float*)d_in[5];
  const float* bfc = (const float*)d_in[6];
  float* out = (float*)d_out;

  char* ws = (char*)d_ws;
  unsigned int*   xproj = (unsigned int*)ws;                         // 128 MB (f16 pairs)
  unsigned short* h_all = (unsigned short*)(ws + 134217728);         // 32 MB (f16)
  unsigned int*   whhT3 = (unsigned int*)(ws + 134217728 + 33554432);// 512 KB (chunked)
  unsigned int*   wfc16 = whhT3 + 131072;                            // 32 KB
  float*          bsum  = (float*)(wfc16 + 8192);                    // 4 KB

  prep_kernel<<<548, 256, 0, stream>>>(Whh, Wfc, bih, bhh, whhT3, wfc16, bsum);
  dim3 gb(512, 16);
  xproj_kernel<<<gb, 256, 0, stream>>>(x, Wih, bsum, xproj);
  int dyn = (HOFF + 256) * 4;   // 99,328 B dynamic LDS
  hipFuncSetAttribute((const void*)lstm_kernel, hipFuncAttributeMaxDynamicSharedMemorySize, dyn);
  lstm_kernel<<<32, 512, dyn, stream>>>(whhT3, xproj, h_all);
  fc_softmax_kernel<<<4096, 1024, 0, stream>>>(h_all, wfc16, bfc, out);
}